// Round 22
// baseline (111.408 us; speedup 1.0000x reference)
//
#include <hip/hip_runtime.h>
#include <math.h>

#define HW2   62
#define NANCH 34596   // 62*62*9
#define NBAT  16
#define NGT   8
#define FEATC 256
#define NOUT  45      // 9 cls + 36 box channels
#define NBLK_C 496    // fused conv blocks = 31 bands * 16 batch

typedef short bf16x8 __attribute__((ext_vector_type(8)));
typedef float f32x4  __attribute__((ext_vector_type(4)));
typedef float f32x2  __attribute__((ext_vector_type(2)));

#define AS1U(p) ((const __attribute__((address_space(1))) unsigned int*)(p))
#define AS3U(p) ((__attribute__((address_space(3))) unsigned int*)(p))

// fp32 -> bf16 round-to-nearest-even (scalar)
__device__ __forceinline__ unsigned short f2bf(float f) {
    unsigned int u = __float_as_uint(f);
    u = u + 0x7FFFu + ((u >> 16) & 1u);
    return (unsigned short)(u >> 16);
}

// packed fp32x2 -> bf16x2 (RNE), single HW instruction (R12-proven)
__device__ __forceinline__ unsigned int pk_bf16(float lo, float hi) {
    unsigned int r;
    asm("v_cvt_pk_bf16_f32 %0, %1, %2" : "=v"(r) : "v"(lo), "v"(hi));
    return r;
}

// ---------- shared device helpers (bitwise identical to passing R2-R21) ----------

__device__ __forceinline__ void anchor4(int i, int j, int a,
                                        float& x1, float& y1, float& x2, float& y2) {
    int am = a % 3, ad = a / 3;
    float h = 2.f * (float)(am + 1);              // 2,4,6
    float w = h * 0.5f * (float)(1 << ad);        // h*{0.5,1,2}
    float cx = (float)i + 0.5f, cy = (float)j + 0.5f;
    x1 = fminf(fmaxf(cx - 0.5f * w, 0.f), 62.f);
    x2 = fminf(fmaxf(cx + 0.5f * w, 0.f), 62.f);
    y1 = fminf(fmaxf(cy - 0.5f * h, 0.f), 62.f);
    y2 = fminf(fmaxf(cy + 0.5f * h, 0.f), 62.f);
}

__device__ __forceinline__ float iou_fn(float ax1, float ay1, float ax2, float ay2,
                                        float gx1, float gy1, float gx2, float gy2) {
    float area_a = __fmul_rn(__fsub_rn(ax2, ax1), __fsub_rn(ay2, ay1));
    float area_g = __fmul_rn(__fsub_rn(gx2, gx1), __fsub_rn(gy2, gy1));
    float ix1 = fmaxf(ax1, gx1), iy1 = fmaxf(ay1, gy1);
    float ix2 = fminf(ax2, gx2), iy2 = fminf(ay2, gy2);
    float iw = fmaxf(__fsub_rn(ix2, ix1), 0.f);
    float ih = fmaxf(__fsub_rn(iy2, iy1), 0.f);
    float inter = __fmul_rn(iw, ih);
    float uni = __fsub_rn(__fadd_rn(area_a, area_g), inter);
    return inter / fmaxf(uni, 1e-9f);
}

__device__ __forceinline__ float softplus_f(float x) {
    return fmaxf(x, 0.f) + log1pf(expf(-fabsf(x)));
}

__device__ __forceinline__ float sl1_f(float d) {
    float ad = fabsf(d);
    return (ad < 1.f) ? 0.5f * d * d : (ad - 0.5f);
}

// ---------- Kernel 1: prep_all (fold | gt max-iou | effb) — no transpose ----------
// blocks [0,432): Bfrag direct fold (R18-proven); [432,560): gt max; [560]: effb
__global__ void prep_all(const float* __restrict__ conv_w,
                         const float* __restrict__ conv_b,
                         const float* __restrict__ cls_w,
                         const float* __restrict__ cls_b,
                         const float* __restrict__ box_w,
                         const float* __restrict__ box_b,
                         const float* __restrict__ gtb,
                         unsigned short* __restrict__ Bfrag,
                         float* __restrict__ effb,
                         float* __restrict__ maxiou) {
    __shared__ float red[256];
    int blk = blockIdx.x, t = threadIdx.x;
    if (blk < 432) {
        int i = blk * 256 + t;               // < 110592 = 48*2304
        int o = i / 2304, idx = i - o * 2304;
        float s = 0.f;
        if (o < NOUT) {
            const float* w2 = (o < 9) ? (cls_w + o * FEATC) : (box_w + (o - 9) * FEATC);
#pragma unroll 8
            for (int m = 0; m < FEATC; ++m)
                s = fmaf(w2[m], conv_w[(size_t)m * 2304 + idx], s);  // w2 uniform, conv_w coalesced
        }
        int c = idx / 9, tap = idx - c * 9;
        size_t slot = (((size_t)(c >> 5) * 9 + tap) * 3 + (o >> 4)) * 512
                    + (size_t)((((c >> 3) & 3) * 16) + (o & 15)) * 8 + (c & 7);
        Bfrag[slot] = f2bf(s);
    } else if (blk < 560) {
        int bg = blk - 432;
        int b = bg >> 3, g = bg & 7;
        const float* p = gtb + (b * NGT + g) * 4;
        float gx1 = p[0] * 0.125f, gy1 = p[1] * 0.125f;
        float gx2 = p[2] * 0.125f, gy2 = p[3] * 0.125f;
        float m = 0.f;
        for (int n = t; n < NANCH; n += 256) {
            int i = n / 558; int r = n - i * 558; int j = r / 9; int a = r - j * 9;
            float ax1, ay1, ax2, ay2;
            anchor4(i, j, a, ax1, ay1, ax2, ay2);
            m = fmaxf(m, iou_fn(ax1, ay1, ax2, ay2, gx1, gy1, gx2, gy2));
        }
        red[t] = m;
        __syncthreads();
        for (int s = 128; s > 0; s >>= 1) {
            if (t < s) red[t] = fmaxf(red[t], red[t + s]);
            __syncthreads();
        }
        if (t == 0) maxiou[bg] = red[0];
    } else {
        if (t < 48) {
            float bv = 0.f;
            if (t < NOUT) {
                bv = (t < 9) ? cls_b[t] : box_b[t - 9];
                const float* w2 = (t < 9) ? (cls_w + t * FEATC) : (box_w + (t - 9) * FEATC);
                for (int mid = 0; mid < FEATC; ++mid) bv = fmaf(w2[mid], conv_b[mid], bv);
            }
            effb[t] = bv;
        }
    }
}

// ---------- Kernel 2: fused MFMA conv — R21 structure, A direct from fp32 feat ----------
// grid 496 = 31 bands x 16 batch (XCD-swizzled), 512 threads (8 waves).
// Block = 2 output rows (124 px). Wave (slot = w&3, kg = w>>2):
//   slot picks 32 pixels (2 m-frags x 3 n-frags); kg picks K-half (4 chunks).
// A: 8 channel-strided fp32 loads + v_cvt_pk_bf16_f32 per frag (R12-proven) —
// no ft tensor, transpose pass deleted. B staged per block via global_load_lds.
__launch_bounds__(512, 4)
__global__ void conv_fused(const float* __restrict__ feat,
                           const unsigned short* __restrict__ Bfrag,
                           const float* __restrict__ effb,
                           const float* __restrict__ gtb,
                           const int* __restrict__ gtc,
                           const float* __restrict__ maxiou,
                           float* __restrict__ outp,
                           float* __restrict__ blksums) {
    __shared__ __align__(16) unsigned char Bs[2][27648];   // Cs/Cs1 overlay after K-loop
    __shared__ float gshr[40];
    __shared__ float wred[8][5];

    float (*Cs)[49]  = (float (*)[49])&Bs[0][0];   // kg0 half (+bias)
    float (*Cs1)[49] = (float (*)[49])&Bs[1][0];   // kg1 half

    const int t = threadIdx.x, l = t & 63, w = t >> 6;
    const int l15 = l & 15, lq = l >> 4;
    const int slot = w & 3, kg = w >> 2;

    // XCD swizzle: 496 % 8 == 0 -> simple bijective form
    int cpx = gridDim.x >> 3;
    int wgid = (blockIdx.x & 7) * cpx + (blockIdx.x >> 3);
    const int band = wgid % 31, b = wgid / 31;
    const int y0 = band * 2;

    if (t < 32) gshr[t] = gtb[b * 32 + t] * 0.125f;
    else if (t < 40) gshr[t] = maxiou[b * 8 + (t - 32)];

    f32x4 acc[2][3];
#pragma unroll
    for (int nf = 0; nf < 3; ++nf) {
        float bv = (kg == 0) ? effb[nf * 16 + l15] : 0.f;   // bias only in K-group 0
#pragma unroll
        for (int mf = 0; mf < 2; ++mf)
#pragma unroll
            for (int r2 = 0; r2 < 4; ++r2) acc[mf][nf][r2] = bv;
    }

    // per-thread A pixel bases within a channel plane; clamp pad pixels (124..127)
    int p0 = slot * 32 + l15;      if (p0 > 123) p0 = 123;
    int p1 = slot * 32 + 16 + l15; if (p1 > 123) p1 = 123;
    int rr0 = p0 / 62, c0 = p0 - rr0 * 62;
    int rr1 = p1 / 62, c1 = p1 - rr1 * 62;
    const int abase0 = (y0 + rr0) * 64 + c0;   // float offsets; (y0+rr+dy)<=63 in-bounds
    const int abase1 = (y0 + rr1) * 64 + c1;

    // load 8 channel-strided floats at p, pack to bf16x8 (RNE) — R12-proven
    auto load_pack = [&](const float* p) -> bf16x8 {
        float v[8];
#pragma unroll
        for (int j = 0; j < 8; ++j) v[j] = p[(size_t)j << 12];
        union { unsigned int u[4]; bf16x8 h; } r;
#pragma unroll
        for (int j = 0; j < 4; ++j) r.u[j] = pk_bf16(v[2 * j], v[2 * j + 1]);
        return r.h;
    };

    // ---- K-loop: 4 iterations; both K-groups' chunks staged each iteration ----
    for (int i = 0; i < 4; ++i) {
#pragma unroll
        for (int k = 0; k < 7; ++k) {                 // 3456 units of 16B (2 chunks)
            int u = t + k * 512;
            if (u < 3456) {
                int buf = (u >= 1728) ? 1 : 0;
                int idx = u - buf * 1728;
                int cs = buf ? (4 + i) : i;
                __builtin_amdgcn_global_load_lds(
                    AS1U(Bfrag + (size_t)cs * 13824 + (size_t)idx * 8),
                    AS3U(&Bs[buf][0] + idx * 16), 16, 0, 0);
            }
        }
        __syncthreads();                              // both chunks resident

        int cc = kg * 4 + i;
        const float* fc = feat + (((size_t)(b * 256 + cc * 32 + lq * 8)) << 12);
        const unsigned char* Bb = &Bs[kg][0];
#pragma unroll
        for (int dy = 0; dy < 3; ++dy) {
            // batch the 6 A-fragment gathers (+pack) for this dy, then its 18 MFMAs
            const float* f0 = fc + abase0 + dy * 64;
            const float* f1 = fc + abase1 + dy * 64;
            bf16x8 a0[3], a1[3];
#pragma unroll
            for (int dx = 0; dx < 3; ++dx) {
                a0[dx] = load_pack(f0 + dx);
                a1[dx] = load_pack(f1 + dx);
            }
            __builtin_amdgcn_sched_barrier(0);
#pragma unroll
            for (int dx = 0; dx < 3; ++dx) {
                int tap = dy * 3 + dx;
#pragma unroll
                for (int nf = 0; nf < 3; ++nf) {
                    bf16x8 bfr = *(const bf16x8*)(Bb + (((tap * 3 + nf) << 6) + l) * 16);
                    acc[0][nf] = __builtin_amdgcn_mfma_f32_16x16x32_bf16(a0[dx], bfr, acc[0][nf], 0, 0, 0);
                    acc[1][nf] = __builtin_amdgcn_mfma_f32_16x16x32_bf16(a1[dx], bfr, acc[1][nf], 0, 0, 0);
                }
            }
        }
        __syncthreads();                              // all waves done before restage
    }

    // ---- write both K-halves to separate LDS regions (no RMW, one barrier) ----
    {
        float (*Cdst)[49] = (kg == 0) ? Cs : Cs1;
#pragma unroll
        for (int mf = 0; mf < 2; ++mf)
#pragma unroll
            for (int nf = 0; nf < 3; ++nf)
#pragma unroll
                for (int r2 = 0; r2 < 4; ++r2) {
                    int pix = slot * 32 + mf * 16 + lq * 4 + r2;
                    if (pix < 124) Cdst[pix][nf * 16 + l15] = acc[mf][nf][r2];
                }
    }
    __syncthreads();

    // ---- fused per-anchor epilogue: 2x62 pixels x 9 anchors = 1116 anchors ----
    float s_pos = 0.f, s_neg = 0.f, s_pl = 0.f, s_nl = 0.f, s_reg = 0.f;
    float* out_prop = outp + 2;
    float* out_mask = out_prop + (size_t)NBAT * NANCH * 4;
    float* out_gtc  = out_mask + (size_t)NBAT * NANCH * 8;

    for (int k = 0; k < 3; ++k) {
        int an = k * 512 + t;
        if (an < 1116) {
            int pixloc = an / 9, a = an - pixloc * 9;
            int rr = pixloc / 62, col = pixloc - rr * 62;
            int oy = y0 + rr, ox = col;
            int n = oy * 558 + ox * 9 + a;
            float cls = Cs[pixloc][a]          + Cs1[pixloc][a];
            float p0f = Cs[pixloc][9 + 4 * a]  + Cs1[pixloc][9 + 4 * a];
            float p1f = Cs[pixloc][10 + 4 * a] + Cs1[pixloc][10 + 4 * a];
            float p2f = Cs[pixloc][11 + 4 * a] + Cs1[pixloc][11 + 4 * a];
            float p3f = Cs[pixloc][12 + 4 * a] + Cs1[pixloc][12 + 4 * a];

            float ax1, ay1, ax2, ay2;
            anchor4(oy, ox, a, ax1, ay1, ax2, ay2);
            float aw = ax2 - ax1, ah = ay2 - ay1;
            float acx = 0.5f * (ax1 + ax2), acy = 0.5f * (ay1 + ay2);

            const float ps = 64.f / 62.f;
            float pcx = acx + p0f * aw, pcy = acy + p1f * ah;
            float pw = aw * expf(p2f), ph = ah * expf(p3f);
            float* pp = out_prop + ((size_t)b * NANCH + n) * 4;
            f32x2 pr0 = { (pcx - 0.5f * pw) * ps, (pcy - 0.5f * ph) * ps };
            f32x2 pr1 = { (pcx + 0.5f * pw) * ps, (pcy + 0.5f * ph) * ps };
            *(f32x2*)(pp) = pr0;
            *(f32x2*)(pp + 2) = pr1;

            float law = logf(aw), lah = logf(ah);
            float posf_tot = 0.f, negf_tot = 0.f;
            float best_iou = -1.f; int best_g = 0;
            float pfv[8];
#pragma unroll
            for (int g = 0; g < NGT; ++g) {
                float gx1 = gshr[g * 4 + 0], gy1 = gshr[g * 4 + 1];
                float gx2 = gshr[g * 4 + 2], gy2 = gshr[g * 4 + 3];
                float iou = iou_fn(ax1, ay1, ax2, ay2, gx1, gy1, gx2, gy2);
                float mpg = gshr[32 + g];
                bool pm = ((iou == mpg) && (mpg > 0.f)) || (iou > 0.7f);
                float pf = pm ? 1.f : 0.f;
                float nf = (iou < 0.3f) ? 1.f : 0.f;
                pfv[g] = pf;
                posf_tot += pf; negf_tot += nf;
                if (iou > best_iou) { best_iou = iou; best_g = g; }  // first-max-wins
                if (pm) {
                    float gw = gx2 - gx1, gh = gy2 - gy1;
                    float gcx = 0.5f * (gx1 + gx2), gcy = 0.5f * (gy1 + gy2);
                    float tx_ = (gcx - acx) / aw, ty_ = (gcy - acy) / ah;
                    float tw_ = logf(gw) - law, th_ = logf(gh) - lah;
                    float d0 = p0f - tx_, d1 = p1f - ty_, d2 = p2f - tw_, d3 = p3f - th_;
                    s_reg += sl1_f(d0) + sl1_f(d1) + sl1_f(d2) + sl1_f(d3);
                }
            }
            float* mp = out_mask + ((size_t)b * NANCH + n) * 8;
#pragma unroll
            for (int g = 0; g < 8; g += 2) {
                f32x2 mv = { pfv[g], pfv[g + 1] };
                *(f32x2*)(mp + g) = mv;
            }
            s_pos += posf_tot; s_neg += negf_tot;
            s_pl += softplus_f(-cls) * posf_tot;
            s_nl += softplus_f(cls) * negf_tot;
            out_gtc[(size_t)b * NANCH + n] = (float)gtc[b * NGT + best_g];
        }
    }

    // ---- loss reduction: per-wave shuffle butterfly + one LDS stage (1 barrier) ----
    int blk = b * 31 + band;   // nblk = 496
    float vals[5] = {s_pos, s_neg, s_pl, s_nl, s_reg};
#pragma unroll
    for (int s = 0; s < 5; ++s) {
        float v = vals[s];
#pragma unroll
        for (int m = 32; m >= 1; m >>= 1) v += __shfl_xor(v, m, 64);
        if (l == 0) wred[w][s] = v;
    }
    __syncthreads();
    if (t < 40) {
        int s = t >> 3, ww = t & 7;
        float v = wred[ww][s];
        v += __shfl_xor(v, 4, 64);
        v += __shfl_xor(v, 2, 64);
        v += __shfl_xor(v, 1, 64);
        if (ww == 0) blksums[(size_t)s * NBLK_C + blk] = v;
    }
}

// ---------- Kernel 3: finalize (1 block; stream order = coherence) ----------
__global__ void finalize(const float* __restrict__ blksums, float* __restrict__ outp) {
    __shared__ float red[256];
    __shared__ float tot[5];
    int t = threadIdx.x;
#pragma unroll
    for (int s = 0; s < 5; ++s) {
        float a = 0.f;
        for (int i = t; i < NBLK_C; i += 256) a += blksums[(size_t)s * NBLK_C + i];
        red[t] = a;
        __syncthreads();
        for (int st = 128; st > 0; st >>= 1) {
            if (t < st) red[t] += red[t + st];
            __syncthreads();
        }
        if (t == 0) tot[s] = red[0];
        __syncthreads();
    }
    if (t == 0) {
        float np_ = fmaxf(tot[0], 1.f), nn_ = fmaxf(tot[1], 1.f);
        outp[0] = 0.5f * (tot[2] / np_ + tot[3] / nn_);  // cls_loss
        outp[1] = tot[4] / (np_ * 4.f);                  // reg_loss
    }
}

extern "C" void kernel_launch(void* const* d_in, const int* in_sizes, int n_in,
                              void* d_out, int out_size, void* d_ws, size_t ws_size,
                              hipStream_t stream) {
    (void)in_sizes; (void)n_in; (void)out_size; (void)ws_size;
    const float* feat   = (const float*)d_in[0];
    const float* gtb    = (const float*)d_in[1];
    const int*   gtc    = (const int*)d_in[2];
    const float* conv_w = (const float*)d_in[3];
    const float* conv_b = (const float*)d_in[4];
    const float* cls_w  = (const float*)d_in[5];
    const float* cls_b  = (const float*)d_in[6];
    const float* box_w  = (const float*)d_in[7];
    const float* box_b  = (const float*)d_in[8];
    float* outp = (float*)d_out;
    float* ws   = (float*)d_ws;

    // workspace layout (floats), ~250 KB total (no ft tensor)
    unsigned short* Bfrag   = (unsigned short*)ws;             // 110592 us = 55296 fl
    float*          effb    = ws + 55296;                      // 64
    float*          maxiou  = ws + 55360;                      // 128
    float*          blksums = ws + 55488;                      // 5*496 = 2480

    prep_all<<<561, 256, 0, stream>>>(conv_w, conv_b, cls_w, cls_b,
                                      box_w, box_b, gtb, Bfrag, effb, maxiou);
    conv_fused<<<NBLK_C, 512, 0, stream>>>(feat, Bfrag, effb, gtb, gtc, maxiou,
                                           outp, blksums);
    finalize<<<1, 256, 0, stream>>>(blksums, outp);
}

// Round 23
// 64.754 us; speedup vs baseline: 1.7205x; 1.7205x over previous
//
#include <hip/hip_runtime.h>
#include <math.h>

#define HW2   62
#define NANCH 34596   // 62*62*9
#define NBAT  16
#define NGT   8
#define FEATC 256
#define NOUT  45      // 9 cls + 36 box channels
#define NBLK_C 496    // fused conv blocks = 31 bands * 16 batch

typedef short bf16x8 __attribute__((ext_vector_type(8)));
typedef float f32x4  __attribute__((ext_vector_type(4)));
typedef float f32x2  __attribute__((ext_vector_type(2)));

#define AS1U(p) ((const __attribute__((address_space(1))) unsigned int*)(p))
#define AS3U(p) ((__attribute__((address_space(3))) unsigned int*)(p))

// fp32 -> bf16 round-to-nearest-even
__device__ __forceinline__ unsigned short f2bf(float f) {
    unsigned int u = __float_as_uint(f);
    u = u + 0x7FFFu + ((u >> 16) & 1u);
    return (unsigned short)(u >> 16);
}

// ---------- shared device helpers (bitwise identical to passing R2-R21) ----------

__device__ __forceinline__ void anchor4(int i, int j, int a,
                                        float& x1, float& y1, float& x2, float& y2) {
    int am = a % 3, ad = a / 3;
    float h = 2.f * (float)(am + 1);              // 2,4,6
    float w = h * 0.5f * (float)(1 << ad);        // h*{0.5,1,2}
    float cx = (float)i + 0.5f, cy = (float)j + 0.5f;
    x1 = fminf(fmaxf(cx - 0.5f * w, 0.f), 62.f);
    x2 = fminf(fmaxf(cx + 0.5f * w, 0.f), 62.f);
    y1 = fminf(fmaxf(cy - 0.5f * h, 0.f), 62.f);
    y2 = fminf(fmaxf(cy + 0.5f * h, 0.f), 62.f);
}

__device__ __forceinline__ float iou_fn(float ax1, float ay1, float ax2, float ay2,
                                        float gx1, float gy1, float gx2, float gy2) {
    float area_a = __fmul_rn(__fsub_rn(ax2, ax1), __fsub_rn(ay2, ay1));
    float area_g = __fmul_rn(__fsub_rn(gx2, gx1), __fsub_rn(gy2, gy1));
    float ix1 = fmaxf(ax1, gx1), iy1 = fmaxf(ay1, gy1);
    float ix2 = fminf(ax2, gx2), iy2 = fminf(ay2, gy2);
    float iw = fmaxf(__fsub_rn(ix2, ix1), 0.f);
    float ih = fmaxf(__fsub_rn(iy2, iy1), 0.f);
    float inter = __fmul_rn(iw, ih);
    float uni = __fsub_rn(__fadd_rn(area_a, area_g), inter);
    return inter / fmaxf(uni, 1e-9f);
}

__device__ __forceinline__ float softplus_f(float x) {
    return fmaxf(x, 0.f) + log1pf(expf(-fabsf(x)));
}

__device__ __forceinline__ float sl1_f(float d) {
    float ad = fabsf(d);
    return (ad < 1.f) ? 0.5f * d * d : (ad - 0.5f);
}

// ---------- to_bf16 body: fp32 NCHW -> bf16 [b][cc][cg][y][x][8ch] ----------
__device__ __forceinline__ void to_bf16_body(const float* __restrict__ feat,
                                             unsigned short* __restrict__ ft,
                                             float* ldsT,
                                             int yp, int cc, int bz, int b, int t) {
    int y0 = yp * 2;
#pragma unroll
    for (int k = 0; k < 4; ++k) {
        int fi = k * 256 + t;
        int ch = fi >> 5, r = fi & 31;
        int y = r >> 4, xq = r & 15;
        f32x4 v = *(const f32x4*)(feat + ((size_t)(b * 256 + cc * 32 + ch) << 12)
                                  + (y0 + y) * 64 + xq * 4);
        int word = ch * 128 + y * 64 + ((xq * 4) ^ ((ch & 7) << 3));
        *(f32x4*)(ldsT + word) = v;
    }
    __syncthreads();
    int y = t >> 7, x = (t >> 1) & 63, h2 = t & 1;
    bf16x8 o0, o1;
#pragma unroll
    for (int j = 0; j < 8; ++j) {
        int ch = h2 * 16 + j;
        o0[j] = (short)f2bf(ldsT[ch * 128 + y * 64 + (x ^ ((ch & 7) << 3))]);
    }
#pragma unroll
    for (int j = 0; j < 8; ++j) {
        int ch = h2 * 16 + 8 + j;
        o1[j] = (short)f2bf(ldsT[ch * 128 + y * 64 + (x ^ ((ch & 7) << 3))]);
    }
    unsigned short* ftc = ft + ((size_t)(bz * 8 + cc) << 17);
    size_t p = (size_t)(y0 + y) * 64 + x;
    *(bf16x8*)(ftc + ((size_t)(h2 * 2) * 4096 + p) * 8) = o0;
    *(bf16x8*)(ftc + ((size_t)(h2 * 2 + 1) * 4096 + p) * 8) = o1;
}

// ---------- Kernel 1: prep_all — EXACT R18 form (measured ~20 us) ----------
// blocks [0,432): fold direct; [432,560): gt max; [560]: effb; [561+): transpose
__global__ void prep_all(const float* __restrict__ feat,
                         const float* __restrict__ conv_w,
                         const float* __restrict__ conv_b,
                         const float* __restrict__ cls_w,
                         const float* __restrict__ cls_b,
                         const float* __restrict__ box_w,
                         const float* __restrict__ box_b,
                         const float* __restrict__ gtb,
                         unsigned short* __restrict__ Bfrag,
                         float* __restrict__ effb,
                         float* __restrict__ maxiou,
                         unsigned short* __restrict__ ft) {
    __shared__ float ldsT[4096];
    __shared__ float red[256];
    int blk = blockIdx.x, t = threadIdx.x;
    if (blk < 432) {
        int i = blk * 256 + t;               // < 110592 = 48*2304
        int o = i / 2304, idx = i - o * 2304;
        float s = 0.f;
        if (o < NOUT) {
            const float* w2 = (o < 9) ? (cls_w + o * FEATC) : (box_w + (o - 9) * FEATC);
#pragma unroll 8
            for (int m = 0; m < FEATC; ++m)
                s = fmaf(w2[m], conv_w[(size_t)m * 2304 + idx], s);  // w2 uniform, conv_w coalesced
        }
        int c = idx / 9, tap = idx - c * 9;
        size_t slot = (((size_t)(c >> 5) * 9 + tap) * 3 + (o >> 4)) * 512
                    + (size_t)((((c >> 3) & 3) * 16) + (o & 15)) * 8 + (c & 7);
        Bfrag[slot] = f2bf(s);
    } else if (blk < 560) {
        int bg = blk - 432;
        int b = bg >> 3, g = bg & 7;
        const float* p = gtb + (b * NGT + g) * 4;
        float gx1 = p[0] * 0.125f, gy1 = p[1] * 0.125f;
        float gx2 = p[2] * 0.125f, gy2 = p[3] * 0.125f;
        float m = 0.f;
        for (int n = t; n < NANCH; n += 256) {
            int i = n / 558; int r = n - i * 558; int j = r / 9; int a = r - j * 9;
            float ax1, ay1, ax2, ay2;
            anchor4(i, j, a, ax1, ay1, ax2, ay2);
            m = fmaxf(m, iou_fn(ax1, ay1, ax2, ay2, gx1, gy1, gx2, gy2));
        }
        red[t] = m;
        __syncthreads();
        for (int s = 128; s > 0; s >>= 1) {
            if (t < s) red[t] = fmaxf(red[t], red[t + s]);
            __syncthreads();
        }
        if (t == 0) maxiou[bg] = red[0];
    } else if (blk == 560) {
        if (t < 48) {
            float bv = 0.f;
            if (t < NOUT) {
                bv = (t < 9) ? cls_b[t] : box_b[t - 9];
                const float* w2 = (t < 9) ? (cls_w + t * FEATC) : (box_w + (t - 9) * FEATC);
                for (int mid = 0; mid < FEATC; ++mid) bv = fmaf(w2[mid], conv_b[mid], bv);
            }
            effb[t] = bv;
        }
    } else {
        int u = blk - 561;
        int yp = u & 31, cc = (u >> 5) & 7, bz = u >> 8;
        to_bf16_body(feat, ft, ldsT, yp, cc, bz, bz, t);
    }
}

// ---------- Kernel 2: fused MFMA conv (R20/R21 form, measured ~43.5 us) ----------
__launch_bounds__(512, 4)
__global__ void conv_fused(const unsigned short* __restrict__ ft,
                           const unsigned short* __restrict__ Bfrag,
                           const float* __restrict__ effb,
                           const float* __restrict__ gtb,
                           const int* __restrict__ gtc,
                           const float* __restrict__ maxiou,
                           float* __restrict__ outp,
                           float* __restrict__ blksums) {
    __shared__ __align__(16) unsigned char Bs[2][27648];   // Cs/Cs1 overlay after K-loop
    __shared__ float gshr[40];
    __shared__ float wred[8][5];

    float (*Cs)[49]  = (float (*)[49])&Bs[0][0];   // kg0 half (+bias)
    float (*Cs1)[49] = (float (*)[49])&Bs[1][0];   // kg1 half

    const int t = threadIdx.x, l = t & 63, w = t >> 6;
    const int l15 = l & 15, lq = l >> 4;
    const int slot = w & 3, kg = w >> 2;

    // XCD swizzle: 496 % 8 == 0 -> simple bijective form
    int cpx = gridDim.x >> 3;
    int wgid = (blockIdx.x & 7) * cpx + (blockIdx.x >> 3);
    const int band = wgid % 31, b = wgid / 31;
    const int y0 = band * 2;

    if (t < 32) gshr[t] = gtb[b * 32 + t] * 0.125f;
    else if (t < 40) gshr[t] = maxiou[b * 8 + (t - 32)];

    f32x4 acc[2][3];
#pragma unroll
    for (int nf = 0; nf < 3; ++nf) {
        float bv = (kg == 0) ? effb[nf * 16 + l15] : 0.f;   // bias only in K-group 0
#pragma unroll
        for (int mf = 0; mf < 2; ++mf)
#pragma unroll
            for (int r2 = 0; r2 < 4; ++r2) acc[mf][nf][r2] = bv;
    }

    // per-thread A base offsets (16B units); clamp pad pixels (124..127)
    int p0 = slot * 32 + l15;      if (p0 > 123) p0 = 123;
    int p1 = slot * 32 + 16 + l15; if (p1 > 123) p1 = 123;
    int rr0 = p0 / 62, c0 = p0 - rr0 * 62;
    int rr1 = p1 / 62, c1 = p1 - rr1 * 62;
    const int aoff0 = (lq << 12) + (y0 + rr0) * 64 + c0;   // (y0+rr+dy)<=63: in-bounds
    const int aoff1 = (lq << 12) + (y0 + rr1) * 64 + c1;

    // ---- K-loop: 4 iterations; both K-groups' chunks staged each iteration ----
    for (int i = 0; i < 4; ++i) {
#pragma unroll
        for (int k = 0; k < 7; ++k) {                 // 3456 units of 16B (2 chunks)
            int u = t + k * 512;
            if (u < 3456) {
                int buf = (u >= 1728) ? 1 : 0;
                int idx = u - buf * 1728;
                int cs = buf ? (4 + i) : i;
                __builtin_amdgcn_global_load_lds(
                    AS1U(Bfrag + (size_t)cs * 13824 + (size_t)idx * 8),
                    AS3U(&Bs[buf][0] + idx * 16), 16, 0, 0);
            }
        }
        __syncthreads();                              // both chunks resident

        int cc = kg * 4 + i;
        const unsigned short* ftc = ft + ((size_t)(b * 8 + cc) << 17);
        const unsigned char* Bb = &Bs[kg][0];
#pragma unroll
        for (int dy = 0; dy < 3; ++dy) {
            // batch the 6 A-fragment loads for this dy, then do its 18 MFMAs
            bf16x8 a0[3], a1[3];
#pragma unroll
            for (int dx = 0; dx < 3; ++dx) {
                int d = dy * 64 + dx;
                a0[dx] = *(const bf16x8*)(ftc + (size_t)(aoff0 + d) * 8);
                a1[dx] = *(const bf16x8*)(ftc + (size_t)(aoff1 + d) * 8);
            }
            __builtin_amdgcn_sched_barrier(0);
#pragma unroll
            for (int dx = 0; dx < 3; ++dx) {
                int tap = dy * 3 + dx;
#pragma unroll
                for (int nf = 0; nf < 3; ++nf) {
                    bf16x8 bfr = *(const bf16x8*)(Bb + (((tap * 3 + nf) << 6) + l) * 16);
                    acc[0][nf] = __builtin_amdgcn_mfma_f32_16x16x32_bf16(a0[dx], bfr, acc[0][nf], 0, 0, 0);
                    acc[1][nf] = __builtin_amdgcn_mfma_f32_16x16x32_bf16(a1[dx], bfr, acc[1][nf], 0, 0, 0);
                }
            }
        }
        __syncthreads();                              // all waves done before restage
    }

    // ---- write both K-halves to separate LDS regions (no RMW, one barrier) ----
    {
        float (*Cdst)[49] = (kg == 0) ? Cs : Cs1;
#pragma unroll
        for (int mf = 0; mf < 2; ++mf)
#pragma unroll
            for (int nf = 0; nf < 3; ++nf)
#pragma unroll
                for (int r2 = 0; r2 < 4; ++r2) {
                    int pix = slot * 32 + mf * 16 + lq * 4 + r2;
                    if (pix < 124) Cdst[pix][nf * 16 + l15] = acc[mf][nf][r2];
                }
    }
    __syncthreads();

    // ---- fused per-anchor epilogue: 2x62 pixels x 9 anchors = 1116 anchors ----
    float s_pos = 0.f, s_neg = 0.f, s_pl = 0.f, s_nl = 0.f, s_reg = 0.f;
    float* out_prop = outp + 2;
    float* out_mask = out_prop + (size_t)NBAT * NANCH * 4;
    float* out_gtc  = out_mask + (size_t)NBAT * NANCH * 8;

    for (int k = 0; k < 3; ++k) {
        int an = k * 512 + t;
        if (an < 1116) {
            int pixloc = an / 9, a = an - pixloc * 9;
            int rr = pixloc / 62, col = pixloc - rr * 62;
            int oy = y0 + rr, ox = col;
            int n = oy * 558 + ox * 9 + a;
            float cls = Cs[pixloc][a]          + Cs1[pixloc][a];
            float p0f = Cs[pixloc][9 + 4 * a]  + Cs1[pixloc][9 + 4 * a];
            float p1f = Cs[pixloc][10 + 4 * a] + Cs1[pixloc][10 + 4 * a];
            float p2f = Cs[pixloc][11 + 4 * a] + Cs1[pixloc][11 + 4 * a];
            float p3f = Cs[pixloc][12 + 4 * a] + Cs1[pixloc][12 + 4 * a];

            float ax1, ay1, ax2, ay2;
            anchor4(oy, ox, a, ax1, ay1, ax2, ay2);
            float aw = ax2 - ax1, ah = ay2 - ay1;
            float acx = 0.5f * (ax1 + ax2), acy = 0.5f * (ay1 + ay2);

            const float ps = 64.f / 62.f;
            float pcx = acx + p0f * aw, pcy = acy + p1f * ah;
            float pw = aw * expf(p2f), ph = ah * expf(p3f);
            float* pp = out_prop + ((size_t)b * NANCH + n) * 4;
            f32x2 pr0 = { (pcx - 0.5f * pw) * ps, (pcy - 0.5f * ph) * ps };
            f32x2 pr1 = { (pcx + 0.5f * pw) * ps, (pcy + 0.5f * ph) * ps };
            *(f32x2*)(pp) = pr0;
            *(f32x2*)(pp + 2) = pr1;

            float law = logf(aw), lah = logf(ah);
            float posf_tot = 0.f, negf_tot = 0.f;
            float best_iou = -1.f; int best_g = 0;
            float pfv[8];
#pragma unroll
            for (int g = 0; g < NGT; ++g) {
                float gx1 = gshr[g * 4 + 0], gy1 = gshr[g * 4 + 1];
                float gx2 = gshr[g * 4 + 2], gy2 = gshr[g * 4 + 3];
                float iou = iou_fn(ax1, ay1, ax2, ay2, gx1, gy1, gx2, gy2);
                float mpg = gshr[32 + g];
                bool pm = ((iou == mpg) && (mpg > 0.f)) || (iou > 0.7f);
                float pf = pm ? 1.f : 0.f;
                float nf = (iou < 0.3f) ? 1.f : 0.f;
                pfv[g] = pf;
                posf_tot += pf; negf_tot += nf;
                if (iou > best_iou) { best_iou = iou; best_g = g; }  // first-max-wins
                if (pm) {
                    float gw = gx2 - gx1, gh = gy2 - gy1;
                    float gcx = 0.5f * (gx1 + gx2), gcy = 0.5f * (gy1 + gy2);
                    float tx_ = (gcx - acx) / aw, ty_ = (gcy - acy) / ah;
                    float tw_ = logf(gw) - law, th_ = logf(gh) - lah;
                    float d0 = p0f - tx_, d1 = p1f - ty_, d2 = p2f - tw_, d3 = p3f - th_;
                    s_reg += sl1_f(d0) + sl1_f(d1) + sl1_f(d2) + sl1_f(d3);
                }
            }
            float* mp = out_mask + ((size_t)b * NANCH + n) * 8;
#pragma unroll
            for (int g = 0; g < 8; g += 2) {
                f32x2 mv = { pfv[g], pfv[g + 1] };
                *(f32x2*)(mp + g) = mv;
            }
            s_pos += posf_tot; s_neg += negf_tot;
            s_pl += softplus_f(-cls) * posf_tot;
            s_nl += softplus_f(cls) * negf_tot;
            out_gtc[(size_t)b * NANCH + n] = (float)gtc[b * NGT + best_g];
        }
    }

    // ---- loss reduction: per-wave shuffle butterfly + one LDS stage (1 barrier) ----
    int blk = b * 31 + band;   // nblk = 496
    float vals[5] = {s_pos, s_neg, s_pl, s_nl, s_reg};
#pragma unroll
    for (int s = 0; s < 5; ++s) {
        float v = vals[s];
#pragma unroll
        for (int m = 32; m >= 1; m >>= 1) v += __shfl_xor(v, m, 64);
        if (l == 0) wred[w][s] = v;
    }
    __syncthreads();
    if (t < 40) {
        int s = t >> 3, ww = t & 7;
        float v = wred[ww][s];
        v += __shfl_xor(v, 4, 64);
        v += __shfl_xor(v, 2, 64);
        v += __shfl_xor(v, 1, 64);
        if (ww == 0) blksums[(size_t)s * NBLK_C + blk] = v;
    }
}

// ---------- Kernel 3: finalize (1 block; stream order = coherence) ----------
__global__ void finalize(const float* __restrict__ blksums, float* __restrict__ outp) {
    __shared__ float red[256];
    __shared__ float tot[5];
    int t = threadIdx.x;
#pragma unroll
    for (int s = 0; s < 5; ++s) {
        float a = 0.f;
        for (int i = t; i < NBLK_C; i += 256) a += blksums[(size_t)s * NBLK_C + i];
        red[t] = a;
        __syncthreads();
        for (int st = 128; st > 0; st >>= 1) {
            if (t < st) red[t] += red[t + st];
            __syncthreads();
        }
        if (t == 0) tot[s] = red[0];
        __syncthreads();
    }
    if (t == 0) {
        float np_ = fmaxf(tot[0], 1.f), nn_ = fmaxf(tot[1], 1.f);
        outp[0] = 0.5f * (tot[2] / np_ + tot[3] / nn_);  // cls_loss
        outp[1] = tot[4] / (np_ * 4.f);                  // reg_loss
    }
}

extern "C" void kernel_launch(void* const* d_in, const int* in_sizes, int n_in,
                              void* d_out, int out_size, void* d_ws, size_t ws_size,
                              hipStream_t stream) {
    (void)in_sizes; (void)n_in; (void)out_size; (void)ws_size;
    const float* feat   = (const float*)d_in[0];
    const float* gtb    = (const float*)d_in[1];
    const int*   gtc    = (const int*)d_in[2];
    const float* conv_w = (const float*)d_in[3];
    const float* conv_b = (const float*)d_in[4];
    const float* cls_w  = (const float*)d_in[5];
    const float* cls_b  = (const float*)d_in[6];
    const float* box_w  = (const float*)d_in[7];
    const float* box_b  = (const float*)d_in[8];
    float* outp = (float*)d_out;
    float* ws   = (float*)d_ws;

    // workspace layout (floats), ~17 MB total
    unsigned short* Bfrag   = (unsigned short*)ws;             // 110592 us = 55296 fl
    float*          effb    = ws + 55296;                      // 64
    float*          maxiou  = ws + 55360;                      // 128
    float*          blksums = ws + 55488;                      // 5*496 = 2480 -> pad 2560
    unsigned short* ft      = (unsigned short*)(ws + 58048);   // 16*1048576 ushorts

    prep_all<<<561 + 4096, 256, 0, stream>>>(feat, conv_w, conv_b, cls_w, cls_b,
                                             box_w, box_b, gtb, Bfrag, effb, maxiou, ft);
    conv_fused<<<NBLK_C, 512, 0, stream>>>(ft, Bfrag, effb, gtb, gtc, maxiou,
                                           outp, blksums);
    finalize<<<1, 256, 0, stream>>>(blksums, outp);
}